// Round 12
// baseline (110.616 us; speedup 1.0000x reference)
//
#include <hip/hip_runtime.h>

#define N_HEAD 16

typedef __attribute__((ext_vector_type(8))) __bf16 bf16x8;
typedef __attribute__((ext_vector_type(8))) short  s16x8;
typedef __attribute__((ext_vector_type(4))) short  s16x4;
typedef __attribute__((ext_vector_type(4))) float  f32x4;
typedef __attribute__((ext_vector_type(4))) unsigned u32x4;

#if __has_builtin(__builtin_amdgcn_exp2f)
#define EXP2(x) __builtin_amdgcn_exp2f(x)
#else
#define EXP2(x) exp2f(x)
#endif
#if __has_builtin(__builtin_amdgcn_rcpf)
#define RCP(x) __builtin_amdgcn_rcpf(x)
#else
#define RCP(x) (1.0f / (x))
#endif

static __device__ __forceinline__ short f2bf(float f) {
    unsigned u = __builtin_bit_cast(unsigned, f);
    unsigned r = (u + 0x7FFFu + ((u >> 16) & 1u)) >> 16;
    return (short)r;
}

static __device__ __forceinline__ unsigned cvt_pk_bf16(float lo, float hi) {
    unsigned d;
    asm("v_cvt_pk_bf16_f32 %0, %1, %2" : "=v"(d) : "v"(lo), "v"(hi));
    return d;
}

static __device__ __forceinline__ void gload_lds16(const void* g, void* l) {
    __builtin_amdgcn_global_load_lds(
        (const __attribute__((address_space(1))) void*)g,
        (__attribute__((address_space(3))) void*)l, 16, 0, 0);
}

#define BARX() do { asm volatile("" ::: "memory"); __builtin_amdgcn_s_barrier(); \
                    asm volatile("" ::: "memory"); } while (0)
#define VMCNT4() asm volatile("s_waitcnt vmcnt(4)" ::: "memory")
#define VMCNT0() asm volatile("s_waitcnt vmcnt(0)" ::: "memory")

// --------------------------------------------- merged pre-pass: cvt + 2 transposes
__global__ __launch_bounds__(256) void prep(
    const float* __restrict__ X,  short* __restrict__ Xb,
    const float* __restrict__ Wa, short* __restrict__ Wat,
    const float* __restrict__ Wp, short* __restrict__ Wpt)
{
    __shared__ short Ts[64][72];
    const int bid = blockIdx.x, tid = threadIdx.x;
    if (bid < 2048) {               // X -> bf16 (4M elements)
        size_t base = ((size_t)bid * 256 + tid) * 8;
        float4 f0 = *(const float4*)&X[base];
        float4 f1 = *(const float4*)&X[base + 4];
        s16x8 o;
        o[0] = f2bf(f0.x); o[1] = f2bf(f0.y); o[2] = f2bf(f0.z); o[3] = f2bf(f0.w);
        o[4] = f2bf(f1.x); o[5] = f2bf(f1.y); o[6] = f2bf(f1.z); o[7] = f2bf(f1.w);
        *(s16x8*)&Xb[base] = o;
        return;
    }
    const float* W; short* Wt; int N, n0, k0;
    if (bid < 2816) { int rr = bid - 2048; W = Wa; Wt = Wat; N = 3072; n0 = (rr % 48) * 64; k0 = (rr / 48) * 64; }
    else            { int rr = bid - 2816; W = Wp; Wt = Wpt; N = 1024; n0 = (rr % 16) * 64; k0 = (rr / 16) * 64; }
    const int r = tid >> 4, c4 = (tid & 15) * 4;
#pragma unroll
    for (int i = 0; i < 4; ++i) {
        int row = r + i * 16;
        float4 f = *(const float4*)&W[(size_t)(k0 + row) * N + n0 + c4];
        s16x4 s = { f2bf(f.x), f2bf(f.y), f2bf(f.z), f2bf(f.w) };
        *(s16x4*)&Ts[row][c4] = s;
    }
    __syncthreads();
#pragma unroll
    for (int i = 0; i < 4; ++i) {
        int row = r + i * 16;
        s16x4 s = { Ts[c4 + 0][row], Ts[c4 + 1][row], Ts[c4 + 2][row], Ts[c4 + 3][row] };
        *(s16x4*)&Wt[(size_t)(n0 + row) * 1024 + k0 + c4] = s;
    }
}

// ---------------------------------------------------------------- GEMM 1: qkv
// 128^2 tile, 3-buffer staging, counted vmcnt(4), chunk^=(row>>1)&3 swizzle.
__global__ __launch_bounds__(256) void qkv_gemm(
    const short* __restrict__ Xb,
    const short* __restrict__ Wt,
    const float* __restrict__ bias,
    short* __restrict__ Qo, short* __restrict__ Ko, short* __restrict__ Vo)
{
    __shared__ short As[3 * 4096];
    __shared__ short Bs[3 * 4096];
    const int tid = threadIdx.x, wave = tid >> 6, lane = tid & 63;
    const int row0 = blockIdx.x * 128, col0 = blockIdx.y * 128;
    const int srow = wave * 16 + (lane >> 2);
    const int sc = (((lane & 3) ^ ((lane >> 3) & 3)) * 8);
    const short* aS = Xb + (size_t)(row0 + srow) * 1024 + sc;
    const short* bS = Wt + (size_t)(col0 + srow) * 1024 + sc;
    const int woff = wave * 512;
    const int wr = (wave >> 1) * 64, wc = (wave & 1) * 64;
    const int arow = lane & 15, g = lane >> 4;
    const int foff = (g ^ ((arow >> 1) & 3)) * 8;

    f32x4 acc[4][4] = {};

#define STAGE(T, BUF) do { const size_t _k = (size_t)(T) * 32; \
    gload_lds16(aS + _k,             As + (BUF) * 4096 + woff); \
    gload_lds16(aS + _k + 64 * 1024, As + (BUF) * 4096 + woff + 2048); \
    gload_lds16(bS + _k,             Bs + (BUF) * 4096 + woff); \
    gload_lds16(bS + _k + 64 * 1024, Bs + (BUF) * 4096 + woff + 2048); \
} while (0)

#define COMPUTE(BUF) do { \
    bf16x8 af[4], bfr[4]; \
    _Pragma("unroll") \
    for (int i = 0; i < 4; ++i) af[i]  = *(const bf16x8*)&As[(BUF) * 4096 + (wr + i * 16 + arow) * 32 + foff]; \
    _Pragma("unroll") \
    for (int j = 0; j < 4; ++j) bfr[j] = *(const bf16x8*)&Bs[(BUF) * 4096 + (wc + j * 16 + arow) * 32 + foff]; \
    _Pragma("unroll") \
    for (int i = 0; i < 4; ++i) \
        _Pragma("unroll") \
        for (int j = 0; j < 4; ++j) \
            acc[i][j] = __builtin_amdgcn_mfma_f32_16x16x32_bf16(af[i], bfr[j], acc[i][j], 0, 0, 0); \
} while (0)

    STAGE(0, 0); STAGE(1, 1);
    VMCNT4(); BARX();

    int cur = 0;
    for (int t = 0; t < 30; ++t) {
        int nbuf = cur + 2; if (nbuf >= 3) nbuf -= 3;
        STAGE(t + 2, nbuf);
        COMPUTE(cur);
        VMCNT4(); BARX();
        cur = (cur == 2) ? 0 : cur + 1;
    }
    COMPUTE(cur); VMCNT0(); BARX();
    cur = (cur == 2) ? 0 : cur + 1;
    COMPUTE(cur);
#undef STAGE
#undef COMPUTE

    const int which = col0 >> 10;
    const int bb = row0 >> 11;
    const int ccol = arow, crow = g * 4;
#pragma unroll
    for (int j = 0; j < 4; ++j) {
        int n = col0 + wc + j * 16 + ccol;
        float bv = bias[n];
        int nc = n & 1023, head = nc >> 6, hd = nc & 63;
        if (which == 0) {
#pragma unroll
            for (int i = 0; i < 4; ++i) {
                int t0 = (row0 & 2047) + wr + i * 16 + crow;
#pragma unroll
                for (int r = 0; r < 4; ++r)
                    Qo[((size_t)(bb * N_HEAD + head) * 2048 + t0 + r) * 64 + hd] =
                        f2bf((acc[i][j][r] + bv) * 0.18033688f);
            }
        } else if (which == 1) {
#pragma unroll
            for (int i = 0; i < 4; ++i) {
                int t0 = (row0 & 2047) + wr + i * 16 + crow;
#pragma unroll
                for (int r = 0; r < 4; ++r)
                    Ko[((size_t)(bb * N_HEAD + head) * 2048 + t0 + r) * 64 + hd] =
                        f2bf(acc[i][j][r] + bv);
            }
        } else {
#pragma unroll
            for (int i = 0; i < 4; ++i) {
                int t0 = (row0 & 2047) + wr + i * 16 + crow;
                s16x4 ov = { f2bf(acc[i][j][0] + bv), f2bf(acc[i][j][1] + bv),
                             f2bf(acc[i][j][2] + bv), f2bf(acc[i][j][3] + bv) };
                *(s16x4*)&Vo[((size_t)(bb * N_HEAD + head) * 64 + hd) * 2048 + t0] = ov;
            }
        }
    }
}

// ---------------------------------------------------------- flash attention v7
// v4b's PROVEN 2-qf inner loop (shared kf/vf, P in registers) in R10's proven
// geometry: 2-wave blocks x 32 q-rows = 64-row tiles, 1024 blocks (4/CU),
// balanced qt mapping. Staging: each wave covers 32 K/V rows via 4 calls;
// kappa offsets for LDS rows rho,+8,+16,+24 are kappa,+16,+4,+20.
__global__ __launch_bounds__(128) void attn_kernel(
    const short* __restrict__ Q, const short* __restrict__ K,
    const short* __restrict__ Vt, short* __restrict__ Y)
{
    __shared__ short Ks[2][4096];
    __shared__ short Vs[2][4096];
    const int bh = blockIdx.x;
    const int by = blockIdx.y, ba = by >> 3, bq = by & 7;
    const int qt = (ba == 0) ? bq : (ba == 1) ? (31 - bq) : (ba == 2) ? (8 + bq) : (23 - bq);
    const int q0 = qt * 64;
    const int b = bh >> 4, h = bh & 15;
    const short* Qh = Q  + (size_t)bh * 2048 * 64;
    const short* Kh = K  + (size_t)bh * 2048 * 64;
    const short* Vh = Vt + (size_t)bh * 64 * 2048;
    const int tid = threadIdx.x, wave = tid >> 6, lane = tid & 63;
    const int qrow0 = q0 + wave * 32;
    const int arow = lane & 15, g = lane >> 4;

    // staging: wave covers tile rows [wave*32, wave*32+32), 4 calls (+0,+8,+16,+24)
    const int rho = wave * 32 + (lane >> 3);
    const int kappa = ((rho >> 5) << 5) | (((rho >> 2) & 3) << 3)
                    | (((rho >> 4) & 1) << 2) | (rho & 3);
    const int xchunk = 8 * ((lane & 7) ^ (rho & 7));
    const short* kSrc = Kh + (size_t)kappa * 64 + xchunk;
    const short* vSrc = Vh + (size_t)rho * 2048 + xchunk;

#define STAGE_KV(BUF, KT) do { \
    short* kD = Ks[BUF] + wave * 2048; \
    short* vD = Vs[BUF] + wave * 2048; \
    const short* kS = kSrc + (size_t)(KT) * 64; \
    const short* vS = vSrc + (KT); \
    gload_lds16(kS,        kD);        gload_lds16(kS + 1024, kD + 512); \
    gload_lds16(kS + 256,  kD + 1024); gload_lds16(kS + 1280, kD + 1536); \
    gload_lds16(vS,             vD);        gload_lds16(vS + 8  * 2048, vD + 512); \
    gload_lds16(vS + 16 * 2048, vD + 1024); gload_lds16(vS + 24 * 2048, vD + 1536); \
} while (0)

    bf16x8 qfr[2][2];
#pragma unroll
    for (int qf = 0; qf < 2; ++qf)
#pragma unroll
        for (int c = 0; c < 2; ++c)
            qfr[qf][c] = *(const bf16x8*)&Qh[(size_t)(qrow0 + qf * 16 + arow) * 64 + c * 32 + (g * 8)];

    f32x4 o[2][4] = {};
    float lsum[2] = {};

    const int nt = qt + 1;

    STAGE_KV(0, 0);
    __syncthreads();

    int cur = 0;
    for (int t = 0; t < nt; ++t) {
        const int kt = t << 6;
        if (t + 1 < nt) STAGE_KV(cur ^ 1, kt + 64);
        if (kt <= qrow0 + 31) {
            const short* Kc = Ks[cur];
            const short* Vc = Vs[cur];
            const bool need_mask = (kt + 64) > qrow0;
            f32x4 s[2][4] = {};
            __builtin_amdgcn_s_setprio(1);
#pragma unroll
            for (int kc = 0; kc < 4; ++kc) {
                int krow = kc * 16 + arow;
                int xr = krow & 7;
#pragma unroll
                for (int c = 0; c < 2; ++c) {
                    bf16x8 kf = *(const bf16x8*)&Kc[krow * 64 + (((c * 4 + g) ^ xr) * 8)];
#pragma unroll
                    for (int qf = 0; qf < 2; ++qf)
                        s[qf][kc] = __builtin_amdgcn_mfma_f32_16x16x32_bf16(kf, qfr[qf][c], s[qf][kc], 0, 0, 0);
                }
            }
            __builtin_amdgcn_s_setprio(0);
            if (need_mask) {
#pragma unroll
                for (int qf = 0; qf < 2; ++qf) {
                    int q = qrow0 + qf * 16 + arow;
#pragma unroll
                    for (int kc = 0; kc < 4; ++kc) {
                        int keyb = kt + ((kc >> 1) << 5) + (g << 3) + ((kc & 1) << 2);
#pragma unroll
                        for (int r = 0; r < 4; ++r)
                            if (keyb + r > q) s[qf][kc][r] = -3.0e38f;
                    }
                }
            }
            unsigned pa[2][8];
#pragma unroll
            for (int qf = 0; qf < 2; ++qf) {
#pragma unroll
                for (int kc = 0; kc < 4; ++kc) {
                    float p0 = EXP2(s[qf][kc][0]);
                    float p1 = EXP2(s[qf][kc][1]);
                    float p2 = EXP2(s[qf][kc][2]);
                    float p3 = EXP2(s[qf][kc][3]);
                    lsum[qf] += (p0 + p1) + (p2 + p3);
                    pa[qf][kc * 2 + 0] = cvt_pk_bf16(p0, p1);
                    pa[qf][kc * 2 + 1] = cvt_pk_bf16(p2, p3);
                }
            }
            __builtin_amdgcn_s_setprio(1);
#pragma unroll
            for (int c = 0; c < 2; ++c) {
                bf16x8 pb0 = __builtin_bit_cast(bf16x8,
                    (u32x4){ pa[0][4 * c], pa[0][4 * c + 1], pa[0][4 * c + 2], pa[0][4 * c + 3] });
                bf16x8 pb1 = __builtin_bit_cast(bf16x8,
                    (u32x4){ pa[1][4 * c], pa[1][4 * c + 1], pa[1][4 * c + 2], pa[1][4 * c + 3] });
#pragma unroll
                for (int j = 0; j < 4; ++j) {
                    int d = j * 16 + arow;
                    bf16x8 vf = *(const bf16x8*)&Vc[d * 64 + (((c * 4 + g) ^ (d & 7)) * 8)];
                    o[0][j] = __builtin_amdgcn_mfma_f32_16x16x32_bf16(vf, pb0, o[0][j], 0, 0, 0);
                    o[1][j] = __builtin_amdgcn_mfma_f32_16x16x32_bf16(vf, pb1, o[1][j], 0, 0, 0);
                }
            }
            __builtin_amdgcn_s_setprio(0);
        }
        __syncthreads();
        cur ^= 1;
    }
#undef STAGE_KV

#pragma unroll
    for (int qf = 0; qf < 2; ++qf) {
        float l = lsum[qf];
        l += __shfl_xor(l, 16);
        l += __shfl_xor(l, 32);
        float li = RCP(l);
        int t = qrow0 + qf * 16 + arow;
#pragma unroll
        for (int j = 0; j < 4; ++j) {
            s16x4 ov = { f2bf(o[qf][j][0] * li), f2bf(o[qf][j][1] * li),
                         f2bf(o[qf][j][2] * li), f2bf(o[qf][j][3] * li) };
            *(s16x4*)&Y[((size_t)(b * 2048 + t)) * 1024 + h * 64 + j * 16 + 4 * g] = ov;
        }
    }
}

// ---------------------------------------------------------------- GEMM 2: proj
// 2-buffer syncthreads double-buffer + chunk swizzle.
__global__ __launch_bounds__(256) void proj_gemm(
    const short* __restrict__ Yb,
    const short* __restrict__ Wpt,
    const float* __restrict__ bias,
    float* __restrict__ Out)
{
    __shared__ short As[2][4096];
    __shared__ short Bs[2][4096];
    const int tid = threadIdx.x, wave = tid >> 6, lane = tid & 63;
    const int row0 = blockIdx.x * 128, col0 = blockIdx.y * 128;
    const int srow = wave * 16 + (lane >> 2);
    const int sc = (((lane & 3) ^ ((lane >> 3) & 3)) * 8);
    const short* aS = Yb  + (size_t)(row0 + srow) * 1024 + sc;
    const short* bS = Wpt + (size_t)(col0 + srow) * 1024 + sc;
    const int woff = wave * 512;
    const int wr = (wave >> 1) * 64, wc = (wave & 1) * 64;
    const int arow = lane & 15, g = lane >> 4;
    const int foff = (g ^ ((arow >> 1) & 3)) * 8;

    f32x4 acc[4][4] = {};

    gload_lds16(aS,             As[0] + woff);
    gload_lds16(aS + 64 * 1024, As[0] + woff + 2048);
    gload_lds16(bS,             Bs[0] + woff);
    gload_lds16(bS + 64 * 1024, Bs[0] + woff + 2048);
    __syncthreads();

    int cur = 0;
    for (int k0 = 0; k0 < 1024; k0 += 32) {
        if (k0 + 32 < 1024) {
            gload_lds16(aS + k0 + 32,             As[cur ^ 1] + woff);
            gload_lds16(aS + k0 + 32 + 64 * 1024, As[cur ^ 1] + woff + 2048);
            gload_lds16(bS + k0 + 32,             Bs[cur ^ 1] + woff);
            gload_lds16(bS + k0 + 32 + 64 * 1024, Bs[cur ^ 1] + woff + 2048);
        }
        bf16x8 af[4], bfr[4];
#pragma unroll
        for (int i = 0; i < 4; ++i) af[i]  = *(const bf16x8*)&As[cur][(wr + i * 16 + arow) * 32 + foff];
#pragma unroll
        for (int j = 0; j < 4; ++j) bfr[j] = *(const bf16x8*)&Bs[cur][(wc + j * 16 + arow) * 32 + foff];
#pragma unroll
        for (int i = 0; i < 4; ++i)
#pragma unroll
            for (int j = 0; j < 4; ++j)
                acc[i][j] = __builtin_amdgcn_mfma_f32_16x16x32_bf16(af[i], bfr[j], acc[i][j], 0, 0, 0);
        __syncthreads();
        cur ^= 1;
    }

    const int ccol = arow, crow = g * 4;
#pragma unroll
    for (int i = 0; i < 4; ++i)
#pragma unroll
        for (int j = 0; j < 4; ++j)
#pragma unroll
            for (int r = 0; r < 4; ++r) {
                int m = row0 + wr + i * 16 + crow + r;
                int n = col0 + wc + j * 16 + ccol;
                Out[(size_t)m * 1024 + n] = acc[i][j][r] + bias[n];
            }
}

// ------------------------------------------------------------------- launch
extern "C" void kernel_launch(void* const* d_in, const int* in_sizes, int n_in,
                              void* d_out, int out_size, void* d_ws, size_t ws_size,
                              hipStream_t stream) {
    const float* x      = (const float*)d_in[0];
    const float* W_attn = (const float*)d_in[1];
    const float* b_attn = (const float*)d_in[2];
    const float* W_proj = (const float*)d_in[3];
    const float* b_proj = (const float*)d_in[4];
    float* out = (float*)d_out;

    short* Xb  = (short*)d_ws;          // dead after qkv -> aliased by yb
    short* Wat = Xb + 4194304;          // 3072x1024
    short* Wpt = Wat + 3145728;         // 1024x1024
    short* qb  = Wpt + 1048576;
    short* kb  = qb + 4194304;
    short* vb  = kb + 4194304;          // V^T: [bh][d][t]
    short* yb  = Xb;                    // attn output (B,T,C) bf16

    prep<<<3072, 256, 0, stream>>>(x, Xb, W_attn, Wat, W_proj, Wpt);
    qkv_gemm<<<dim3(32, 24), 256, 0, stream>>>(Xb, Wat, b_attn, qb, kb, vb);
    attn_kernel<<<dim3(32, 32), 128, 0, stream>>>(qb, kb, vb, yb);
    proj_gemm<<<dim3(32, 8), 256, 0, stream>>>(yb, Wpt, b_proj, out);
}

// Round 13
// 103.196 us; speedup vs baseline: 1.0719x; 1.0719x over previous
//
#include <hip/hip_runtime.h>

#define N_HEAD 16

typedef __attribute__((ext_vector_type(8))) __bf16 bf16x8;
typedef __attribute__((ext_vector_type(8))) short  s16x8;
typedef __attribute__((ext_vector_type(4))) short  s16x4;
typedef __attribute__((ext_vector_type(4))) float  f32x4;
typedef __attribute__((ext_vector_type(4))) unsigned u32x4;

#if __has_builtin(__builtin_amdgcn_exp2f)
#define EXP2(x) __builtin_amdgcn_exp2f(x)
#else
#define EXP2(x) exp2f(x)
#endif
#if __has_builtin(__builtin_amdgcn_rcpf)
#define RCP(x) __builtin_amdgcn_rcpf(x)
#else
#define RCP(x) (1.0f / (x))
#endif

static __device__ __forceinline__ short f2bf(float f) {
    unsigned u = __builtin_bit_cast(unsigned, f);
    unsigned r = (u + 0x7FFFu + ((u >> 16) & 1u)) >> 16;
    return (short)r;
}

static __device__ __forceinline__ unsigned cvt_pk_bf16(float lo, float hi) {
    unsigned d;
    asm("v_cvt_pk_bf16_f32 %0, %1, %2" : "=v"(d) : "v"(lo), "v"(hi));
    return d;
}

static __device__ __forceinline__ void gload_lds16(const void* g, void* l) {
    __builtin_amdgcn_global_load_lds(
        (const __attribute__((address_space(1))) void*)g,
        (__attribute__((address_space(3))) void*)l, 16, 0, 0);
}

#define BARX() do { asm volatile("" ::: "memory"); __builtin_amdgcn_s_barrier(); \
                    asm volatile("" ::: "memory"); } while (0)
#define VMCNT4() asm volatile("s_waitcnt vmcnt(4)" ::: "memory")
#define VMCNT0() asm volatile("s_waitcnt vmcnt(0)" ::: "memory")

// --------------------------------------------- merged pre-pass: cvt + 2 transposes
__global__ __launch_bounds__(256) void prep(
    const float* __restrict__ X,  short* __restrict__ Xb,
    const float* __restrict__ Wa, short* __restrict__ Wat,
    const float* __restrict__ Wp, short* __restrict__ Wpt)
{
    __shared__ short Ts[64][72];
    const int bid = blockIdx.x, tid = threadIdx.x;
    if (bid < 2048) {               // X -> bf16 (4M elements)
        size_t base = ((size_t)bid * 256 + tid) * 8;
        float4 f0 = *(const float4*)&X[base];
        float4 f1 = *(const float4*)&X[base + 4];
        s16x8 o;
        o[0] = f2bf(f0.x); o[1] = f2bf(f0.y); o[2] = f2bf(f0.z); o[3] = f2bf(f0.w);
        o[4] = f2bf(f1.x); o[5] = f2bf(f1.y); o[6] = f2bf(f1.z); o[7] = f2bf(f1.w);
        *(s16x8*)&Xb[base] = o;
        return;
    }
    const float* W; short* Wt; int N, n0, k0;
    if (bid < 2816) { int rr = bid - 2048; W = Wa; Wt = Wat; N = 3072; n0 = (rr % 48) * 64; k0 = (rr / 48) * 64; }
    else            { int rr = bid - 2816; W = Wp; Wt = Wpt; N = 1024; n0 = (rr % 16) * 64; k0 = (rr / 16) * 64; }
    const int r = tid >> 4, c4 = (tid & 15) * 4;
#pragma unroll
    for (int i = 0; i < 4; ++i) {
        int row = r + i * 16;
        float4 f = *(const float4*)&W[(size_t)(k0 + row) * N + n0 + c4];
        s16x4 s = { f2bf(f.x), f2bf(f.y), f2bf(f.z), f2bf(f.w) };
        *(s16x4*)&Ts[row][c4] = s;
    }
    __syncthreads();
#pragma unroll
    for (int i = 0; i < 4; ++i) {
        int row = r + i * 16;
        s16x4 s = { Ts[c4 + 0][row], Ts[c4 + 1][row], Ts[c4 + 2][row], Ts[c4 + 3][row] };
        *(s16x4*)&Wt[(size_t)(n0 + row) * 1024 + k0 + c4] = s;
    }
}

// ---------------------------------------------------------------- GEMM 1: qkv
// 128^2 tile, 3-buffer staging, counted vmcnt(4), chunk^=(row>>1)&3 swizzle.
__global__ __launch_bounds__(256) void qkv_gemm(
    const short* __restrict__ Xb,
    const short* __restrict__ Wt,
    const float* __restrict__ bias,
    short* __restrict__ Qo, short* __restrict__ Ko, short* __restrict__ Vo)
{
    __shared__ short As[3 * 4096];
    __shared__ short Bs[3 * 4096];
    const int tid = threadIdx.x, wave = tid >> 6, lane = tid & 63;
    const int row0 = blockIdx.x * 128, col0 = blockIdx.y * 128;
    const int srow = wave * 16 + (lane >> 2);
    const int sc = (((lane & 3) ^ ((lane >> 3) & 3)) * 8);
    const short* aS = Xb + (size_t)(row0 + srow) * 1024 + sc;
    const short* bS = Wt + (size_t)(col0 + srow) * 1024 + sc;
    const int woff = wave * 512;
    const int wr = (wave >> 1) * 64, wc = (wave & 1) * 64;
    const int arow = lane & 15, g = lane >> 4;
    const int foff = (g ^ ((arow >> 1) & 3)) * 8;

    f32x4 acc[4][4] = {};

#define STAGE(T, BUF) do { const size_t _k = (size_t)(T) * 32; \
    gload_lds16(aS + _k,             As + (BUF) * 4096 + woff); \
    gload_lds16(aS + _k + 64 * 1024, As + (BUF) * 4096 + woff + 2048); \
    gload_lds16(bS + _k,             Bs + (BUF) * 4096 + woff); \
    gload_lds16(bS + _k + 64 * 1024, Bs + (BUF) * 4096 + woff + 2048); \
} while (0)

#define COMPUTE(BUF) do { \
    bf16x8 af[4], bfr[4]; \
    _Pragma("unroll") \
    for (int i = 0; i < 4; ++i) af[i]  = *(const bf16x8*)&As[(BUF) * 4096 + (wr + i * 16 + arow) * 32 + foff]; \
    _Pragma("unroll") \
    for (int j = 0; j < 4; ++j) bfr[j] = *(const bf16x8*)&Bs[(BUF) * 4096 + (wc + j * 16 + arow) * 32 + foff]; \
    _Pragma("unroll") \
    for (int i = 0; i < 4; ++i) \
        _Pragma("unroll") \
        for (int j = 0; j < 4; ++j) \
            acc[i][j] = __builtin_amdgcn_mfma_f32_16x16x32_bf16(af[i], bfr[j], acc[i][j], 0, 0, 0); \
} while (0)

    STAGE(0, 0); STAGE(1, 1);
    VMCNT4(); BARX();

    int cur = 0;
    for (int t = 0; t < 30; ++t) {
        int nbuf = cur + 2; if (nbuf >= 3) nbuf -= 3;
        STAGE(t + 2, nbuf);
        COMPUTE(cur);
        VMCNT4(); BARX();
        cur = (cur == 2) ? 0 : cur + 1;
    }
    COMPUTE(cur); VMCNT0(); BARX();
    cur = (cur == 2) ? 0 : cur + 1;
    COMPUTE(cur);
#undef STAGE
#undef COMPUTE

    const int which = col0 >> 10;
    const int bb = row0 >> 11;
    const int ccol = arow, crow = g * 4;
#pragma unroll
    for (int j = 0; j < 4; ++j) {
        int n = col0 + wc + j * 16 + ccol;
        float bv = bias[n];
        int nc = n & 1023, head = nc >> 6, hd = nc & 63;
        if (which == 0) {
#pragma unroll
            for (int i = 0; i < 4; ++i) {
                int t0 = (row0 & 2047) + wr + i * 16 + crow;
#pragma unroll
                for (int r = 0; r < 4; ++r)
                    Qo[((size_t)(bb * N_HEAD + head) * 2048 + t0 + r) * 64 + hd] =
                        f2bf((acc[i][j][r] + bv) * 0.18033688f);
            }
        } else if (which == 1) {
#pragma unroll
            for (int i = 0; i < 4; ++i) {
                int t0 = (row0 & 2047) + wr + i * 16 + crow;
#pragma unroll
                for (int r = 0; r < 4; ++r)
                    Ko[((size_t)(bb * N_HEAD + head) * 2048 + t0 + r) * 64 + hd] =
                        f2bf(acc[i][j][r] + bv);
            }
        } else {
#pragma unroll
            for (int i = 0; i < 4; ++i) {
                int t0 = (row0 & 2047) + wr + i * 16 + crow;
                s16x4 ov = { f2bf(acc[i][j][0] + bv), f2bf(acc[i][j][1] + bv),
                             f2bf(acc[i][j][2] + bv), f2bf(acc[i][j][3] + bv) };
                *(s16x4*)&Vo[((size_t)(bb * N_HEAD + head) * 64 + hd) * 2048 + t0] = ov;
            }
        }
    }
}

// ---------------------------------------------------------- flash attention v5c
// R10's proven v5b datapath (4 waves x 16 q-rows, 1024 blocks, balanced qt) with
// the per-tile vmcnt(0) drain removed: 2-buffer + counted vmcnt(4) + raw barriers.
// Per iter: compute(buf[t&1]); barrier; STAGE(t+2 -> buf[t&1]); vmcnt(4); barrier.
// STAGE(t+2)'s 4 loads stay in flight across the next tile's compute.
__global__ __launch_bounds__(256) void attn_kernel(
    const short* __restrict__ Q, const short* __restrict__ K,
    const short* __restrict__ Vt, short* __restrict__ Y)
{
    __shared__ short Ks[2][64 * 64];
    __shared__ short Vs[2][64 * 64];
    const int bh = blockIdx.x;
    const int by = blockIdx.y, ba = by >> 3, bq = by & 7;
    const int qt = (ba == 0) ? bq : (ba == 1) ? (31 - bq) : (ba == 2) ? (8 + bq) : (23 - bq);
    const int q0 = qt * 64;
    const int b = bh >> 4, h = bh & 15;
    const short* Qh = Q  + (size_t)bh * 2048 * 64;
    const short* Kh = K  + (size_t)bh * 2048 * 64;
    const short* Vh = Vt + (size_t)bh * 64 * 2048;
    const int tid = threadIdx.x, wave = tid >> 6, lane = tid & 63;
    const int qrow0 = q0 + wave * 16;
    const int arow = lane & 15, g = lane >> 4;

    const int rho = wave * 16 + (lane >> 3);
    const int kappa = ((rho >> 5) << 5) | (((rho >> 2) & 3) << 3)
                    | (((rho >> 4) & 1) << 2) | (rho & 3);
    const int xchunk = 8 * ((lane & 7) ^ (rho & 7));
    const short* kSrc = Kh + (size_t)kappa * 64 + xchunk;
    const short* vSrc = Vh + (size_t)rho * 2048 + xchunk;

#define STAGE_KV(BUF, KT) do { \
    short* kD = Ks[BUF] + wave * 1024; \
    short* vD = Vs[BUF] + wave * 1024; \
    gload_lds16(kSrc + (size_t)(KT) * 64,        kD); \
    gload_lds16(kSrc + (size_t)(KT) * 64 + 1024, kD + 512); \
    gload_lds16(vSrc + (KT),                     vD); \
    gload_lds16(vSrc + (KT) + 8 * 2048,          vD + 512); \
} while (0)

    bf16x8 qfr[2];
#pragma unroll
    for (int c = 0; c < 2; ++c)
        qfr[c] = *(const bf16x8*)&Qh[(size_t)(qrow0 + arow) * 64 + c * 32 + (g * 8)];

    f32x4 o[4] = {};
    float lsum = 0.f;

    const int nt = qt + 1;

    STAGE_KV(0, 0);
    STAGE_KV(1, 64);
    VMCNT4(); BARX();

    for (int t = 0; t < nt; ++t) {
        const int kt = t << 6;
        const int cur = t & 1;
        if (kt <= qrow0 + 15) {
            const short* Kc = Ks[cur];
            const short* Vc = Vs[cur];
            const bool need_mask = (kt + 64) > qrow0;
            f32x4 s[4] = {};
#pragma unroll
            for (int kc = 0; kc < 4; ++kc) {
                int krow = kc * 16 + arow;
                int xr = krow & 7;
#pragma unroll
                for (int c = 0; c < 2; ++c) {
                    bf16x8 kf = *(const bf16x8*)&Kc[krow * 64 + (((c * 4 + g) ^ xr) * 8)];
                    s[kc] = __builtin_amdgcn_mfma_f32_16x16x32_bf16(kf, qfr[c], s[kc], 0, 0, 0);
                }
            }
            if (need_mask) {
                int q = qrow0 + arow;
#pragma unroll
                for (int kc = 0; kc < 4; ++kc) {
                    int keyb = kt + ((kc >> 1) << 5) + (g << 3) + ((kc & 1) << 2);
#pragma unroll
                    for (int r = 0; r < 4; ++r)
                        if (keyb + r > q) s[kc][r] = -3.0e38f;
                }
            }
            unsigned pa[8];
#pragma unroll
            for (int kc = 0; kc < 4; ++kc) {
                float p0 = EXP2(s[kc][0]);
                float p1 = EXP2(s[kc][1]);
                float p2 = EXP2(s[kc][2]);
                float p3 = EXP2(s[kc][3]);
                lsum += (p0 + p1) + (p2 + p3);
                pa[kc * 2 + 0] = cvt_pk_bf16(p0, p1);
                pa[kc * 2 + 1] = cvt_pk_bf16(p2, p3);
            }
#pragma unroll
            for (int c = 0; c < 2; ++c) {
                bf16x8 pb = __builtin_bit_cast(bf16x8,
                    (u32x4){ pa[4 * c], pa[4 * c + 1], pa[4 * c + 2], pa[4 * c + 3] });
#pragma unroll
                for (int j = 0; j < 4; ++j) {
                    int d = j * 16 + arow;
                    bf16x8 vf = *(const bf16x8*)&Vc[d * 64 + (((c * 4 + g) ^ (d & 7)) * 8)];
                    o[j] = __builtin_amdgcn_mfma_f32_16x16x32_bf16(vf, pb, o[j], 0, 0, 0);
                }
            }
        }
        BARX();                       // all waves done reading buf[cur]
        if (t + 2 < nt) {
            STAGE_KV(cur, kt + 128);  // refill the buffer just consumed
            VMCNT4();                 // wait only for STAGE(t+1); t+2 stays in flight
        } else {
            VMCNT0();                 // tail: ensure last staged tile is complete
        }
        BARX();                       // all waves' STAGE(t+1) visible
    }
#undef STAGE_KV

    {
        float l = lsum;
        l += __shfl_xor(l, 16);
        l += __shfl_xor(l, 32);
        float li = RCP(l);
        int t = qrow0 + arow;
#pragma unroll
        for (int j = 0; j < 4; ++j) {
            s16x4 ov = { f2bf(o[j][0] * li), f2bf(o[j][1] * li),
                         f2bf(o[j][2] * li), f2bf(o[j][3] * li) };
            *(s16x4*)&Y[((size_t)(b * 2048 + t)) * 1024 + h * 64 + j * 16 + 4 * g] = ov;
        }
    }
}

// ---------------------------------------------------------------- GEMM 2: proj
// 2-buffer syncthreads double-buffer + chunk swizzle.
__global__ __launch_bounds__(256) void proj_gemm(
    const short* __restrict__ Yb,
    const short* __restrict__ Wpt,
    const float* __restrict__ bias,
    float* __restrict__ Out)
{
    __shared__ short As[2][4096];
    __shared__ short Bs[2][4096];
    const int tid = threadIdx.x, wave = tid >> 6, lane = tid & 63;
    const int row0 = blockIdx.x * 128, col0 = blockIdx.y * 128;
    const int srow = wave * 16 + (lane >> 2);
    const int sc = (((lane & 3) ^ ((lane >> 3) & 3)) * 8);
    const short* aS = Yb  + (size_t)(row0 + srow) * 1024 + sc;
    const short* bS = Wpt + (size_t)(col0 + srow) * 1024 + sc;
    const int woff = wave * 512;
    const int wr = (wave >> 1) * 64, wc = (wave & 1) * 64;
    const int arow = lane & 15, g = lane >> 4;
    const int foff = (g ^ ((arow >> 1) & 3)) * 8;

    f32x4 acc[4][4] = {};

    gload_lds16(aS,             As[0] + woff);
    gload_lds16(aS + 64 * 1024, As[0] + woff + 2048);
    gload_lds16(bS,             Bs[0] + woff);
    gload_lds16(bS + 64 * 1024, Bs[0] + woff + 2048);
    __syncthreads();

    int cur = 0;
    for (int k0 = 0; k0 < 1024; k0 += 32) {
        if (k0 + 32 < 1024) {
            gload_lds16(aS + k0 + 32,             As[cur ^ 1] + woff);
            gload_lds16(aS + k0 + 32 + 64 * 1024, As[cur ^ 1] + woff + 2048);
            gload_lds16(bS + k0 + 32,             Bs[cur ^ 1] + woff);
            gload_lds16(bS + k0 + 32 + 64 * 1024, Bs[cur ^ 1] + woff + 2048);
        }
        bf16x8 af[4], bfr[4];
#pragma unroll
        for (int i = 0; i < 4; ++i) af[i]  = *(const bf16x8*)&As[cur][(wr + i * 16 + arow) * 32 + foff];
#pragma unroll
        for (int j = 0; j < 4; ++j) bfr[j] = *(const bf16x8*)&Bs[cur][(wc + j * 16 + arow) * 32 + foff];
#pragma unroll
        for (int i = 0; i < 4; ++i)
#pragma unroll
            for (int j = 0; j < 4; ++j)
                acc[i][j] = __builtin_amdgcn_mfma_f32_16x16x32_bf16(af[i], bfr[j], acc[i][j], 0, 0, 0);
        __syncthreads();
        cur ^= 1;
    }

    const int ccol = arow, crow = g * 4;
#pragma unroll
    for (int i = 0; i < 4; ++i)
#pragma unroll
        for (int j = 0; j < 4; ++j)
#pragma unroll
            for (int r = 0; r < 4; ++r) {
                int m = row0 + wr + i * 16 + crow + r;
                int n = col0 + wc + j * 16 + ccol;
                Out[(size_t)m * 1024 + n] = acc[i][j][r] + bias[n];
            }
}

// ------------------------------------------------------------------- launch
extern "C" void kernel_launch(void* const* d_in, const int* in_sizes, int n_in,
                              void* d_out, int out_size, void* d_ws, size_t ws_size,
                              hipStream_t stream) {
    const float* x      = (const float*)d_in[0];
    const float* W_attn = (const float*)d_in[1];
    const float* b_attn = (const float*)d_in[2];
    const float* W_proj = (const float*)d_in[3];
    const float* b_proj = (const float*)d_in[4];
    float* out = (float*)d_out;

    short* Xb  = (short*)d_ws;          // dead after qkv -> aliased by yb
    short* Wat = Xb + 4194304;          // 3072x1024
    short* Wpt = Wat + 3145728;         // 1024x1024
    short* qb  = Wpt + 1048576;
    short* kb  = qb + 4194304;
    short* vb  = kb + 4194304;          // V^T: [bh][d][t]
    short* yb  = Xb;                    // attn output (B,T,C) bf16

    prep<<<3072, 256, 0, stream>>>(x, Xb, W_attn, Wat, W_proj, Wpt);
    qkv_gemm<<<dim3(32, 24), 256, 0, stream>>>(Xb, Wat, b_attn, qb, kb, vb);
    attn_kernel<<<dim3(32, 32), 256, 0, stream>>>(qb, kb, vb, yb);
    proj_gemm<<<dim3(32, 8), 256, 0, stream>>>(yb, Wpt, b_proj, out);
}